// Round 7
// baseline (1794.672 us; speedup 1.0000x reference)
//
#include <hip/hip_runtime.h>
#include <math.h>

// ---------------- problem constants ----------------
constexpr int NSWEEP = 5;   // 6 and 8 gave bit-identical absmax (floor) -> 5

// ws offsets (in floats)
constexpr size_t OFF_SUMX   = 0;        // 22
constexpr size_t OFF_G      = 22;       // 253
constexpr size_t OFF_SUM2   = 288;      // 20
constexpr size_t OFF_SUMSQ2 = 308;      // 20
constexpr size_t OFF_S2     = 328;      // 20
constexpr size_t OFF_A      = 352;      // 484
constexpr size_t OFF_D      = 840;      // 22
constexpr size_t OFF_WR     = 864;      // 5280 -> 6144
constexpr size_t OFF_COV    = 6144;     // 8192*400 (later reused as `mixed` 8192*324)
constexpr size_t OFF_LQKV   = 3282944;  // 8192*3*324
constexpr size_t OFF_FEAT   = 11245568; // 1024*1368

// ---------------- constexpr tables ----------------
struct Tri { int a[253]; int b[253]; };
constexpr Tri mk_tri(int n) {
    Tri t{}; int c = 0;
    for (int i = 0; i < n; ++i) for (int j = i; j < n; ++j) { t.a[c] = i; t.b[c] = j; ++c; }
    return t;
}
constexpr Tri T22 = mk_tri(22);
constexpr Tri T20 = mk_tri(20);
constexpr Tri T18 = mk_tri(18);

// round-robin (circle method) schedule for n=18: 17 rounds x 9 disjoint pairs, p<q
struct Sched { int p[17][9]; int q[17][9]; };
constexpr Sched mk_sched() {
    Sched s{};
    for (int r = 0; r < 17; ++r)
        for (int k = 0; k < 9; ++k) {
            int x, y;
            if (k == 0) { x = 17; y = r; }
            else { x = (r + k) % 17; y = (r - k + 17) % 17; }
            s.p[r][k] = x < y ? x : y;
            s.q[r][k] = x < y ? y : x;
        }
    return s;
}
constexpr Sched SCH = mk_sched();

// ---------------- wave-parallel 18x18 Jacobi eigh (v7 = v6 + per-round sched fence) ----------------
// Lane (within wave) = base + jj holds column jj of A (a[i] = A[i][jj]) and
// ROW jj of the accumulated eigenvector matrix V (vr[k] = V[jj][k]).
//
// Six-round regalloc map (same math, absmax bit-identical throughout):
//   v1: cc/ss + pt[17]+kt[17] + V-cols (36-shfl col loop)  -> VGPR 104, 612us
//   v4/v6: cc/ss + V-rows (18-shfl col loop)               -> VGPR 136, 697-767us
//   v3/v5: inlined rsq in row loop                         -> VGPR 256 + GB spills
// v6 hand-count is ~70 live regs yet allocator says 136; v1 hand-count ~98
// -> 104. Hypothesis: the mandatory #pragma unroll over 17 rounds lets the
// scheduler software-pipeline ROUNDS when the round body is short (v6's
// 18-shfl tail), keeping ~2 rounds of state live (+60 regs). v1's long
// serialized 36-shfl column exchange incidentally blocked that.
// v7 tests it directly: __builtin_amdgcn_sched_barrier(0) at the end of each
// round — a zero-cost compile-time fence that forbids cross-round motion
// while leaving within-round ILP (9 independent rotations, 18 independent
// shfls) untouched.
// Round-3 lesson stands: never force VGPR via __launch_bounds__ min-waves.
//
// CORRECTNESS INVARIANT: only p-lane tangents are ever used (broadcast);
// every lane of a pair applies bitwise-identical (c,s) in both the row and
// the column update (identical source bits + identical instruction sequence).
//
// Lanes 54..63 run an isolated duplicate of group 2: shfl only pulls, so
// they never contaminate groups 0-2 (and they never write LDS).
__device__ __forceinline__ float jacobi18(float* __restrict__ a, float* __restrict__ vr,
                                          int jj, int base) {
    // byte-packed per-round partner table (17 entries, 5 VGPRs)
    unsigned ptP[5] = {0u, 0u, 0u, 0u, 0u};
#pragma unroll
    for (int r = 0; r < 17; ++r) {
        int k1 = jj - r; if (k1 < 0) k1 += 17;
        int partner;
        if (jj == 17)      { partner = r; }
        else if (k1 == 0)  { partner = 17; }
        else if (k1 <= 8)  { partner = r - k1; if (partner < 0) partner += 17; }
        else               { partner = r + 17 - k1; if (partner >= 17) partner -= 17; }
        ptP[r >> 2] |= (unsigned)partner << ((r & 3) * 8);
    }
    // own diagonal, maintained analytically (used only for rotation decisions;
    // final eigenvalue is read from the true stored a[jj])
    float mydiag = a[0];
#pragma unroll
    for (int i = 1; i < 18; ++i) if (jj == i) mydiag = a[i];

    for (int sw = 0; sw < NSWEEP; ++sw) {
#pragma unroll
        for (int r = 0; r < 17; ++r) {
            const int partner = (int)((ptP[r >> 2] >> ((r & 3) * 8)) & 0xffu);
            const int paddr = base + partner;
            const bool isp = jj < partner;
            const int plane = isp ? jj : partner;   // p-lane (min) of my pair
            // partner's diagonal (1 shfl)
            float pd = __shfl(mydiag, paddr, 64);
            // own off-diagonal apq = a[partner] (18-way select, partner lane-varying)
            float apq = a[0];
#pragma unroll
            for (int i = 1; i < 18; ++i) if (partner == i) apq = a[i];
            float app = isp ? mydiag : pd;
            float aqq = isp ? pd : mydiag;
            // candidate tangent (only the p-lane's version gets used)
            float apqc = (fabsf(apq) < 1e-36f) ? 1e-36f : apq;
            float tau = (aqq - app) * 0.5f * __builtin_amdgcn_rcpf(apqc);
            float t0 = __builtin_amdgcn_rcpf(fabsf(tau) + __builtin_amdgcn_sqrtf(fmaf(tau, tau, 1.f)));
            t0 = (tau < 0.f) ? -t0 : t0;
            // broadcast the 9 pair tangents from p-lanes (9 DS ops)
            float tb[9];
#pragma unroll
            for (int k = 0; k < 9; ++k)
                tb[k] = __shfl(t0, base + SCH.p[r][k], 64);
            // recompute (c,s) locally into arrays — bitwise identical in every
            // lane; MATERIALIZED arrays (inlining the rsq into the row loop is
            // a proven regalloc bomb: VGPR 256 + spills in v3/v5)
            float cc[9], ss[9];
#pragma unroll
            for (int k = 0; k < 9; ++k) {
                cc[k] = __builtin_amdgcn_rsqf(fmaf(tb[k], tb[k], 1.f));
                ss[k] = tb[k] * cc[k];
            }
            // my pair's rotation: same source lane as the tb[] entry for my
            // pair -> identical bits; identical expression -> identical (c,s)
            float mt = __shfl(t0, base + plane, 64);
            float mc = __builtin_amdgcn_rsqf(fmaf(mt, mt, 1.f));
            float ms = mt * mc;
            // analytic diagonal update: A'pp = app - t*apq ; A'qq = aqq + t*apq
            mydiag = fmaf(isp ? -mt : mt, apq, mydiag);
            // row update of A + row update of V (all compile-time indices)
#pragma unroll
            for (int k = 0; k < 9; ++k) {
                const int p = SCH.p[r][k], q = SCH.q[r][k];
                float tp = a[p], tq = a[q];
                a[p] = cc[k] * tp - ss[k] * tq;
                a[q] = ss[k] * tp + cc[k] * tq;
                float vp = vr[p], vq = vr[q];
                vr[p] = cc[k] * vp - ss[k] * vq;
                vr[q] = ss[k] * vp + cc[k] * vq;
            }
            // column update of A via pairwise exchange (same mc/ms bits both lanes)
            float ssig = isp ? -ms : ms;
#pragma unroll
            for (int i = 0; i < 18; ++i) {
                float oa = __shfl(a[i], paddr, 64);
                a[i] = mc * a[i] + ssig * oa;
            }
            // fence: forbid cross-round instruction motion (register-pressure
            // control, zero runtime cost). Within-round ILP is untouched.
            __builtin_amdgcn_sched_barrier(0);
        }
    }
    // eigenvalue = true stored diagonal (no analytic drift)
    float lam = a[0];
#pragma unroll
    for (int i = 1; i < 18; ++i) if (jj == i) lam = a[i];
    return lam;
}

// ---------------- K0: zero atomic accumulators ----------------
__global__ void k0_zero(float* ws) {
    int tid = threadIdx.x;
    for (int i = tid; i < 352; i += 256) ws[i] = 0.f;
}

// ---------------- K1: x channel sums + Gram (for analytic BN1) ----------------
__global__ __launch_bounds__(256) void k1_stats(const float* __restrict__ x,
                                                float* __restrict__ sumx,
                                                float* __restrict__ G) {
    int b = blockIdx.x, tid = threadIdx.x;
    __shared__ float xt[22 * 257];
    float accp = 0.f, accs = 0.f;
    int c1 = 0, c2 = 0;
    if (tid < 253) { c1 = T22.a[tid]; c2 = T22.b[tid]; }
    const float* xb = x + (size_t)b * 22 * 2047;
    for (int t0 = 0; t0 < 2047; t0 += 256) {
        __syncthreads();
        for (int idx = tid; idx < 22 * 256; idx += 256) {
            int c = idx >> 8, tl = idx & 255;
            int t = t0 + tl;
            xt[c * 257 + tl] = (t < 2047) ? xb[c * 2047 + t] : 0.f;
        }
        __syncthreads();
        if (tid < 253) {
            float s = 0.f;
            for (int t = 0; t < 256; ++t) s += xt[c1 * 257 + t] * xt[c2 * 257 + t];
            accp += s;
        }
        if (tid < 22) {
            float s = 0.f;
            for (int t = 0; t < 256; ++t) s += xt[tid * 257 + t];
            accs += s;
        }
    }
    if (tid < 253) atomicAdd(&G[tid], accp);
    if (tid < 22) atomicAdd(&sumx[tid], accs);
}

// ---------------- K2: finalize BN1 -> A = diag(s1)W, d; reorder w_temp ----------------
__global__ __launch_bounds__(256) void k2_prep(const float* __restrict__ w_spat,
                                               const float* __restrict__ b_spat,
                                               const float* __restrict__ g1,
                                               const float* __restrict__ be1,
                                               const float* __restrict__ w_temp,
                                               const float* __restrict__ sumx,
                                               const float* __restrict__ G,
                                               float* __restrict__ A,
                                               float* __restrict__ dv,
                                               float* __restrict__ w_r) {
    int tid = threadIdx.x;
    __shared__ float cov[22 * 22], mux[22], mu1s[22], s1s[22];
    const float invN = 1.f / (1024.f * 2047.f);
    if (tid < 22) mux[tid] = sumx[tid] * invN;
    __syncthreads();
    if (tid < 253) {
        int c1 = T22.a[tid], c2 = T22.b[tid];
        float cv = G[tid] * invN - mux[c1] * mux[c2];
        cov[c1 * 22 + c2] = cv; cov[c2 * 22 + c1] = cv;
    }
    __syncthreads();
    if (tid < 22) {
        int c = tid;
        float m = b_spat[c], varv = 0.f;
        for (int e = 0; e < 22; ++e) m += w_spat[c * 22 + e] * mux[e];
        for (int i = 0; i < 22; ++i) {
            float wi = w_spat[c * 22 + i];
            for (int j = 0; j < 22; ++j) varv += wi * w_spat[c * 22 + j] * cov[i * 22 + j];
        }
        mu1s[c] = m;
        s1s[c] = g1[c] * rsqrtf(varv + 1e-5f);
    }
    __syncthreads();
    for (int idx = tid; idx < 484; idx += 256) {
        int c = idx / 22;
        A[idx] = s1s[c] * w_spat[idx];
    }
    if (tid < 22) dv[tid] = s1s[tid] * (b_spat[tid] - mu1s[tid]) + be1[tid];
    // w_r[(c*12+k)*20 + f] = w_temp[f][c][k]
    for (int idx = tid; idx < 5280; idx += 256) {
        int f = idx / 264, r = idx % 264;
        w_r[r * 20 + f] = w_temp[idx];
    }
}

// ---------------- K3: fused (spatial+BN1) -> temporal conv -> patch raw cov + BN2 stats ----------------
__global__ __launch_bounds__(256) void k3_conv(const float* __restrict__ x,
                                               const float* __restrict__ wsA,
                                               const float* __restrict__ wsd,
                                               const float* __restrict__ w_r,
                                               float* __restrict__ cov_raw,
                                               float* __restrict__ sum2,
                                               float* __restrict__ sumsq2) {
    int bp = blockIdx.x;           // b*8 + p
    int b = bp >> 3, p = bp & 7;
    int tid = threadIdx.x;
    __shared__ float xs[22 * 267];  // x tile, then conv-input (A x + d, zero-padded) in place
    __shared__ float h2[20 * 257];  // conv output tile (b_temp dropped: shift-invariant)
    __shared__ float pm[20];

    const float* xb = x + (size_t)b * 22 * 2047;
    const int t0 = p * 256 - 6;
    for (int idx = tid; idx < 22 * 267; idx += 256) {
        int c = idx / 267, tl = idx % 267;
        int t = t0 + tl;
        xs[idx] = (t >= 0 && t < 2047) ? xb[c * 2047 + t] : 0.f;
    }
    __syncthreads();
    // conv input in place: column per thread
    for (int tl = tid; tl < 267; tl += 256) {
        float xv[22];
#pragma unroll
        for (int c = 0; c < 22; ++c) xv[c] = xs[c * 267 + tl];
        int t = t0 + tl;
        bool valid = (t >= 0 && t < 2047);
#pragma unroll
        for (int c = 0; c < 22; ++c) {
            float acc = wsd[c];
#pragma unroll
            for (int e = 0; e < 22; ++e) acc += wsA[c * 22 + e] * xv[e];
            xs[c * 267 + tl] = valid ? acc : 0.f;
        }
    }
    __syncthreads();
    // temporal conv: thread = output column
    {
        int tl = tid;
        float acc[20];
#pragma unroll
        for (int f = 0; f < 20; ++f) acc[f] = 0.f;
        for (int c = 0; c < 22; ++c) {
#pragma unroll
            for (int k = 0; k < 12; ++k) {
                float hv = xs[c * 267 + tl + k];
                const float* wp = w_r + (c * 12 + k) * 20;   // wave-uniform -> s_load
#pragma unroll
                for (int f = 0; f < 20; ++f) acc[f] += wp[f] * hv;
            }
        }
#pragma unroll
        for (int f = 0; f < 20; ++f) h2[f * 257 + tl] = acc[f];
    }
    __syncthreads();
    // per-patch means + global BN2 accumulators
    if (tid < 20) {
        int f = tid;
        float s = 0.f, ss = 0.f;
        for (int t = 0; t < 256; ++t) { float v = h2[f * 257 + t]; s += v; ss += v * v; }
        pm[f] = s * (1.f / 256.f);
        atomicAdd(&sum2[f], s);
        atomicAdd(&sumsq2[f], ss);
    }
    __syncthreads();
    // raw patch covariance (unnormalized; trace-norm cancels divisors downstream)
    for (int pr = tid; pr < 210; pr += 256) {
        int f = T20.a[pr], g = T20.b[pr];
        float s = 0.f;
        for (int t = 0; t < 256; ++t) s += h2[f * 257 + t] * h2[g * 257 + t];
        float cv = s - 256.f * pm[f] * pm[g];
        cov_raw[(size_t)bp * 400 + f * 20 + g] = cv;
        if (f != g) cov_raw[(size_t)bp * 400 + g * 20 + f] = cv;
    }
}

// ---------------- K4: finalize BN2 scale ----------------
__global__ void k4_s2(const float* __restrict__ g2, const float* __restrict__ sum2,
                      const float* __restrict__ sumsq2, float* __restrict__ s2) {
    int tid = threadIdx.x;
    if (tid < 20) {
        const float invN = 1.f / (1024.f * 2048.f);
        float mu = sum2[tid] * invN;
        float var = sumsq2[tid] * invN - mu * mu;
        s2[tid] = g2[tid] * rsqrtf(var + 1e-5f);
    }
}

// ---------------- K5: BiMap Q/K/V (s2 folded into W), eigh, logm ----------------
// 4 waves per block, one bp per wave. Natural register allocation; target
// VGPR <= 128 (occupancy cliff: >128 halves waves/SIMD 4->2).
__global__ __launch_bounds__(256) void k5_qkv(const float* __restrict__ wq,
                                              const float* __restrict__ wk,
                                              const float* __restrict__ wv,
                                              const float* __restrict__ s2g,
                                              const float* __restrict__ cov_raw,
                                              float* __restrict__ lqkv) {
    int tid = threadIdx.x;
    int wave = tid >> 6;
    int lane = tid & 63;
    int bp = blockIdx.x * 4 + wave;
    __shared__ float Wl[1080];       // [m][18][20], pre-scaled by s2[e] (shared)
    __shared__ float s2l[20];
    __shared__ float covn[4][400];   // per-wave raw patch covariance
    __shared__ float Vs[4][972];     // V row-major [row][col]
    __shared__ float lws[4][54];

    if (tid < 20) s2l[tid] = s2g[tid];
    for (int idx = lane; idx < 400; idx += 64)
        covn[wave][idx] = cov_raw[(size_t)bp * 400 + idx];
    __syncthreads();
    for (int idx = tid; idx < 1080; idx += 256) {
        int m = idx / 360, rem = idx % 360;
        const float* W = (m == 0) ? wq : (m == 1) ? wk : wv;
        Wl[idx] = W[rem] * s2l[rem % 20];
    }
    __syncthreads();

    // trace of s2-scaled cov (broadcast LDS reads, every lane redundantly)
    float tr = 0.f;
#pragma unroll
    for (int f = 0; f < 20; ++f) tr += covn[wave][f * 21] * s2l[f] * s2l[f];
    float trinv = 1.f / tr;

    int grp = lane / 18;
    int jj = lane - grp * 18;
    int m = grp < 3 ? grp : 2;
    int base = grp * 18;
    // Wrow = scaled W_m row jj
    float Wrow[20];
#pragma unroll
    for (int d = 0; d < 20; ++d) Wrow[d] = Wl[m * 360 + jj * 20 + d];
    // u[e] = sum_d covn[e][d] * Wrow[d]  (covn symmetric)
    float u[20];
#pragma unroll
    for (int e = 0; e < 20; ++e) {
        float acc = 0.f;
#pragma unroll
        for (int d = 0; d < 20; ++d) acc += covn[wave][e * 20 + d] * Wrow[d];
        u[e] = acc;
    }
    // a[i] = trinv * sum_e Wl[m][i][e] * u[e];  vr = row jj of identity
    float a[18], vr[18];
#pragma unroll
    for (int i = 0; i < 18; ++i) {
        float acc = 0.f;
#pragma unroll
        for (int e = 0; e < 20; ++e) acc += Wl[m * 360 + i * 20 + e] * u[e];
        a[i] = acc * trinv;
        vr[i] = (i == jj) ? 1.f : 0.f;
    }
    float lam = jacobi18(a, vr, jj, base);
    float lw = __logf(fmaxf(lam, 1e-10f));
    if (grp < 3) {
        // scalar row store: Vs[row=jj][col=i] = V[jj][i]
#pragma unroll
        for (int i = 0; i < 18; ++i) Vs[wave][(m * 18 + jj) * 18 + i] = vr[i];
        lws[wave][m * 18 + jj] = lw;
    }
    __builtin_amdgcn_wave_barrier();   // wave-synchronous LDS: write->read same wave
    // L = V diag(lw) V^T with Vs row-major: L[i][jo] = sum_k V[i][k] lw[k] V[jo][k]
    for (int idx = lane; idx < 972; idx += 64) {
        int m2 = idx / 324, rem = idx % 324, i = rem / 18, jo = rem % 18;
        float acc = 0.f;
#pragma unroll
        for (int kk = 0; kk < 18; ++kk)
            acc += Vs[wave][(m2 * 18 + i) * 18 + kk] * lws[wave][m2 * 18 + kk] * Vs[wave][(m2 * 18 + jo) * 18 + kk];
        lqkv[(size_t)(bp * 3 + m2) * 324 + rem] = acc;
    }
}

// ---------------- K6: log-Euclidean attention -> mixed tangent matrices ----------------
__global__ __launch_bounds__(256) void k6_attn(const float* __restrict__ lqkv,
                                               float* __restrict__ mixed) {
    int b = blockIdx.x, tid = threadIdx.x;
    __shared__ float L[7776];       // [p][m][324]
    __shared__ float sq[8], sk[8], cross[64], prob[64];
    const float* src = lqkv + (size_t)b * 7776;
    for (int idx = tid; idx < 7776; idx += 256) L[idx] = src[idx];
    __syncthreads();
    if (tid < 64) {
        int i = tid >> 3, j = tid & 7;
        const float* fq = &L[(i * 3 + 0) * 324];
        const float* fk = &L[(j * 3 + 1) * 324];
        float cr = 0.f;
        for (int e = 0; e < 324; ++e) cr += fq[e] * fk[e];
        cross[tid] = cr;
    } else if (tid < 72) {
        int i = tid - 64;
        const float* fq = &L[(i * 3 + 0) * 324];
        float s = 0.f;
        for (int e = 0; e < 324; ++e) s += fq[e] * fq[e];
        sq[i] = s;
    } else if (tid < 80) {
        int i = tid - 72;
        const float* fk = &L[(i * 3 + 1) * 324];
        float s = 0.f;
        for (int e = 0; e < 324; ++e) s += fk[e] * fk[e];
        sk[i] = s;
    }
    __syncthreads();
    if (tid < 8) {
        int j = tid;
        float w[8], mx = -1e30f;
        for (int i = 0; i < 8; ++i) {
            float d2 = fmaxf(sq[i] + sk[j] - 2.f * cross[i * 8 + j], 0.0f);
            float en = sqrtf(d2 + 1e-12f);
            w[i] = 1.f / (1.f + log1pf(en));
            mx = fmaxf(mx, w[i]);
        }
        float ssum = 0.f;
        for (int i = 0; i < 8; ++i) { w[i] = __expf(w[i] - mx); ssum += w[i]; }
        float inv = 1.f / ssum;
        for (int i = 0; i < 8; ++i) prob[i * 8 + j] = w[i] * inv;
    }
    __syncthreads();
    float* dst = mixed + (size_t)b * 8 * 324;
    for (int idx = tid; idx < 8 * 324; idx += 256) {
        int j = idx / 324, e = idx % 324;
        float acc = 0.f;
#pragma unroll
        for (int i = 0; i < 8; ++i) acc += prob[i * 8 + j] * L[(i * 3 + 2) * 324 + e];
        dst[idx] = acc;
    }
}

// ---------------- K7: eigh(mixed) -> clamp eigs -> triu vec, Gershgorin fast path ----------------
// 4 waves per block, 3 matrices per wave (12 per block). NO __syncthreads:
// all sync is wave-local (shfl reduce + wave-synchronous LDS slices), so the
// per-wave divergent Gershgorin skip is barrier-safe.
__global__ __launch_bounds__(256) void k7_post(const float* __restrict__ mixed,
                                               float* __restrict__ feat) {
    int tid = threadIdx.x;
    int wave = tid >> 6;
    int lane = tid & 63;
    int blk = blockIdx.x;
    int grp = lane / 18;
    int jj = lane - grp * 18;
    int m = grp < 3 ? grp : 2;
    int base = grp * 18;
    int mat = blk * 12 + wave * 3 + m;
    int matc = mat < 8192 ? mat : 8191;
    __shared__ float Vs[4][972];
    __shared__ float lws[4][54];

    const float* src = mixed + (size_t)matc * 324;
    float a[18], vr[18];
#pragma unroll
    for (int i = 0; i < 18; ++i) {
        a[i] = src[i * 18 + jj];
        vr[i] = (i == jj) ? 1.f : 0.f;
    }
    // Gershgorin lower bound for this column: diag - sum_{i!=jj}|a[i]| = 2*diag - sum|a[i]|
    float diag = a[0], asum = 0.f;
#pragma unroll
    for (int i = 0; i < 18; ++i) {
        if (jj == i) diag = a[i];
        asum += fabsf(a[i]);
    }
    float gb = 2.f * diag - asum;    // lanes 54..63 hold a duplicate of m=2: harmless
    // wave-min butterfly
#pragma unroll
    for (int off = 32; off; off >>= 1) gb = fminf(gb, __shfl_xor(gb, off, 64));
    const bool skipAll = (gb > -9.2103f);   // wave-uniform; clamp is a no-op -> lt == M

    if (!skipAll) {
        float lam = jacobi18(a, vr, jj, base);
        float lw = fmaxf(lam, -9.210340371976182f);   // ln(1e-4)
        if (grp < 3) {
#pragma unroll
            for (int i = 0; i < 18; ++i) Vs[wave][(m * 18 + jj) * 18 + i] = vr[i];
            lws[wave][m * 18 + jj] = lw;
        }
    }
    __builtin_amdgcn_wave_barrier();   // wave-synchronous LDS slice
    for (int idx = lane; idx < 513; idx += 64) {
        int m2 = idx / 171, rem = idx % 171;
        int mat2 = blk * 12 + wave * 3 + m2;
        if (mat2 >= 8192) continue;
        int i = T18.a[rem], jo = T18.b[rem];
        float acc;
        if (skipAll) {
            acc = mixed[(size_t)mat2 * 324 + i * 18 + jo];   // lt == M exactly
        } else {
            acc = 0.f;
#pragma unroll
            for (int kk = 0; kk < 18; ++kk)
                acc += Vs[wave][(m2 * 18 + i) * 18 + kk] * lws[wave][m2 * 18 + kk] * Vs[wave][(m2 * 18 + jo) * 18 + kk];
        }
        float scl = (i == jo) ? 1.f : 1.41421356237309515f;
        int bb = mat2 >> 3, pp = mat2 & 7;
        feat[(size_t)bb * 1368 + pp * 171 + rem] = acc * scl;
    }
}

// ---------------- K8: final linear ----------------
__global__ __launch_bounds__(256) void k8_lin(const float* __restrict__ feat,
                                              const float* __restrict__ w_lin,
                                              const float* __restrict__ b_lin,
                                              float* __restrict__ out) {
    int b = blockIdx.x, tid = threadIdx.x;
    int o = tid >> 6, lane = tid & 63;
    const float* fb = feat + (size_t)b * 1368;
    const float* wo = w_lin + o * 1368;
    float acc = 0.f;
    for (int e = lane; e < 1368; e += 64) acc += fb[e] * wo[e];
    for (int off = 32; off; off >>= 1) acc += __shfl_down(acc, off, 64);
    if (lane == 0) out[b * 4 + o] = acc + b_lin[o];
}

// ---------------- launcher ----------------
extern "C" void kernel_launch(void* const* d_in, const int* in_sizes, int n_in,
                              void* d_out, int out_size, void* d_ws, size_t ws_size,
                              hipStream_t stream) {
    (void)in_sizes; (void)n_in; (void)out_size; (void)ws_size;
    const float* x      = (const float*)d_in[0];
    const float* w_spat = (const float*)d_in[1];
    const float* b_spat = (const float*)d_in[2];
    const float* g1     = (const float*)d_in[3];
    const float* be1    = (const float*)d_in[4];
    const float* w_temp = (const float*)d_in[5];
    // d_in[6] = b_temp : cancels in patch covariance -> unused
    const float* g2     = (const float*)d_in[7];
    // d_in[8] = be2 : cancels -> unused
    const float* wq     = (const float*)d_in[9];
    const float* wk     = (const float*)d_in[10];
    const float* wv     = (const float*)d_in[11];
    const float* w_lin  = (const float*)d_in[12];
    const float* b_lin  = (const float*)d_in[13];
    float* ws  = (float*)d_ws;
    float* out = (float*)d_out;

    k0_zero<<<1, 256, 0, stream>>>(ws);
    k1_stats<<<1024, 256, 0, stream>>>(x, ws + OFF_SUMX, ws + OFF_G);
    k2_prep<<<1, 256, 0, stream>>>(w_spat, b_spat, g1, be1, w_temp,
                                   ws + OFF_SUMX, ws + OFF_G,
                                   ws + OFF_A, ws + OFF_D, ws + OFF_WR);
    k3_conv<<<8192, 256, 0, stream>>>(x, ws + OFF_A, ws + OFF_D, ws + OFF_WR,
                                      ws + OFF_COV, ws + OFF_SUM2, ws + OFF_SUMSQ2);
    k4_s2<<<1, 64, 0, stream>>>(g2, ws + OFF_SUM2, ws + OFF_SUMSQ2, ws + OFF_S2);
    k5_qkv<<<2048, 256, 0, stream>>>(wq, wk, wv, ws + OFF_S2, ws + OFF_COV, ws + OFF_LQKV);
    k6_attn<<<1024, 256, 0, stream>>>(ws + OFF_LQKV, ws + OFF_COV /* mixed reuses cov region */);
    k7_post<<<683, 256, 0, stream>>>(ws + OFF_COV, ws + OFF_FEAT);
    k8_lin<<<1024, 256, 0, stream>>>(ws + OFF_FEAT, w_lin, b_lin, out);
}

// Round 9
// 1583.861 us; speedup vs baseline: 1.1331x; 1.1331x over previous
//
#include <hip/hip_runtime.h>
#include <math.h>

// ---------------- problem constants ----------------
constexpr int NSWEEP = 5;   // 6 and 8 gave bit-identical absmax (floor) -> 5

// ws offsets (in floats)
constexpr size_t OFF_SUMX   = 0;        // 22
constexpr size_t OFF_G      = 22;       // 253
constexpr size_t OFF_SUM2   = 288;      // 20
constexpr size_t OFF_SUMSQ2 = 308;      // 20
constexpr size_t OFF_S2     = 328;      // 20
constexpr size_t OFF_A      = 352;      // 484
constexpr size_t OFF_D      = 840;      // 22
constexpr size_t OFF_WR     = 864;      // 5280 -> 6144
constexpr size_t OFF_COV    = 6144;     // 8192*400 (later reused as `mixed` 8192*324)
constexpr size_t OFF_LQKV   = 3282944;  // 8192*3*324
constexpr size_t OFF_FEAT   = 11245568; // 1024*1368

// ---------------- constexpr tables ----------------
struct Tri { int a[253]; int b[253]; };
constexpr Tri mk_tri(int n) {
    Tri t{}; int c = 0;
    for (int i = 0; i < n; ++i) for (int j = i; j < n; ++j) { t.a[c] = i; t.b[c] = j; ++c; }
    return t;
}
constexpr Tri T22 = mk_tri(22);
constexpr Tri T20 = mk_tri(20);
constexpr Tri T18 = mk_tri(18);

// round-robin (circle method) schedule for n=18: 17 rounds x 9 disjoint pairs, p<q
struct Sched { int p[17][9]; int q[17][9]; };
constexpr Sched mk_sched() {
    Sched s{};
    for (int r = 0; r < 17; ++r)
        for (int k = 0; k < 9; ++k) {
            int x, y;
            if (k == 0) { x = 17; y = r; }
            else { x = (r + k) % 17; y = (r - k + 17) % 17; }
            s.p[r][k] = x < y ? x : y;
            s.q[r][k] = x < y ? y : x;
        }
    return s;
}
constexpr Sched SCH = mk_sched();

// ---------------- wave-parallel 18x18 Jacobi eigh (v8 = v1 + D2 only) ----------------
// Lane (within wave) = base + jj holds column jj (a[i] = A[i][jj]; v[i] = V[i][jj]).
// 3 matrices per wave (bases 0,18,36); lanes 54..63 run an isolated duplicate
// of group 2 (shfl only pulls, so they never contaminate groups 0-2).
//
// SEVEN-ROUND CONCLUSION (all variants bit-identical absmax; k5 times):
//   v1 (this structure + kt-select):        104 VGPR, 612us  <- best
//   v4/v6 (V-as-rows, fewer DS/round):      136 VGPR, 697-767us
//   v7 (v6 + per-round sched_barrier):      104 VGPR, 718us
//   v3/v5 (rsq inlined in row loop):        256 VGPR + GB-scale spills
// k5 is CRITICAL-PATH LATENCY bound (neither DS nor VALU saturated; v1 does
// MORE of both and wins). v1's 18 V-column shfls + 36 V-FMAs per round are
// independent filler that the scheduler overlaps with the next round's
// serial head (pd-shfl -> tau -> t0) at low register cost. Do NOT remove
// them (v4/v6) and do NOT fence the rounds (v7).
// v8's single delta (D2): kt[17] dropped; my pair's tangent arrives via one
// extra shfl issued in parallel with the 9 tb-shfls, and (mc,ms) is
// recomputed with the IDENTICAL expression used for cc/ss -> removes the
// 24-VALU kk-select from the serial path. Validated bit-identical in
// rounds 2/4/5/6.
//
// CORRECTNESS INVARIANT: every lane of a pair applies the bitwise-IDENTICAL
// (c,s) in BOTH the row and the column update. The 9 pair tangents are
// broadcast from p-lanes; (c,s) recomputed redundantly in every lane —
// identical inputs + identical instruction sequence -> identical bits.
// mt = shfl(t0, base+plane) reads the SAME source lane as the tb[] entry
// for my pair -> identical bits; mc/ms use the same fmaf+rsq+mul sequence.
__device__ __forceinline__ float jacobi18(float* __restrict__ a, float* __restrict__ v,
                                          int jj, int base) {
    // per-round partner table (depends only on (r, jj)) — compute once
    int pt[17];
#pragma unroll
    for (int r = 0; r < 17; ++r) {
        int k1 = jj - r; if (k1 < 0) k1 += 17;
        int partner;
        if (jj == 17)      { partner = r; }
        else if (k1 == 0)  { partner = 17; }
        else if (k1 <= 8)  { partner = r - k1; if (partner < 0) partner += 17; }
        else               { partner = r + 17 - k1; if (partner >= 17) partner -= 17; }
        pt[r] = partner;
    }
    // own diagonal, maintained analytically (used only for rotation decisions;
    // final eigenvalue is read from the true stored a[jj])
    float mydiag = a[0];
#pragma unroll
    for (int i = 1; i < 18; ++i) if (jj == i) mydiag = a[i];

    for (int sw = 0; sw < NSWEEP; ++sw) {
#pragma unroll
        for (int r = 0; r < 17; ++r) {
            const int partner = pt[r];
            const int paddr = base + partner;
            const bool isp = jj < partner;
            const int plane = isp ? jj : partner;   // p-lane (min) of my pair
            // partner's diagonal (1 shfl)
            float pd = __shfl(mydiag, paddr, 64);
            // own off-diagonal apq = a[partner] (18-way select, partner lane-varying)
            float apq = a[0];
#pragma unroll
            for (int i = 1; i < 18; ++i) if (partner == i) apq = a[i];
            float app = isp ? mydiag : pd;
            float aqq = isp ? pd : mydiag;
            // candidate tangent (only the p-lane's version gets used)
            float apqc = (fabsf(apq) < 1e-36f) ? 1e-36f : apq;
            float tau = (aqq - app) * 0.5f * __builtin_amdgcn_rcpf(apqc);
            float t0 = __builtin_amdgcn_rcpf(fabsf(tau) + __builtin_amdgcn_sqrtf(fmaf(tau, tau, 1.f)));
            t0 = (tau < 0.f) ? -t0 : t0;
            // broadcast the 9 pair tangents from p-lanes (9 DS ops) + my own
            // pair's tangent (1 DS op, same source lane as my tb[] entry)
            float tb[9];
#pragma unroll
            for (int k = 0; k < 9; ++k)
                tb[k] = __shfl(t0, base + SCH.p[r][k], 64);
            float mt = __shfl(t0, base + plane, 64);
            // recompute (c,s) locally — bitwise identical in every lane
            float cc[9], ss[9];
#pragma unroll
            for (int k = 0; k < 9; ++k) {
                cc[k] = __builtin_amdgcn_rsqf(fmaf(tb[k], tb[k], 1.f));
                ss[k] = tb[k] * cc[k];
            }
            // my pair's (c,s): identical expression + identical input bits as
            // the cc/ss recompute for my pair -> identical rotation bits
            float mc = __builtin_amdgcn_rsqf(fmaf(mt, mt, 1.f));
            float ms = mt * mc;
            // analytic diagonal update: A'pp = app - t*apq ; A'qq = aqq + t*apq
            mydiag = fmaf(isp ? -mt : mt, apq, mydiag);
            // row update (lane-local registers), all 9 disjoint pairs
#pragma unroll
            for (int k = 0; k < 9; ++k) {
                const int p = SCH.p[r][k], q = SCH.q[r][k];
                float tp = a[p], tq = a[q];
                a[p] = cc[k] * tp - ss[k] * tq;
                a[q] = ss[k] * tp + cc[k] * tq;
            }
            // column update with the SAME uniform (mc,ms) via partner exchange.
            // The A and V exchanges are independent filler work that the
            // scheduler overlaps with the next round's serial head — keep them.
            float ssig = isp ? -ms : ms;
#pragma unroll
            for (int i = 0; i < 18; ++i) {
                float oa = __shfl(a[i], paddr, 64);
                a[i] = mc * a[i] + ssig * oa;
            }
#pragma unroll
            for (int i = 0; i < 18; ++i) {
                float ov = __shfl(v[i], paddr, 64);
                v[i] = mc * v[i] + ssig * ov;
            }
        }
    }
    // eigenvalue = true stored diagonal (no analytic drift)
    float lam = a[0];
#pragma unroll
    for (int i = 1; i < 18; ++i) if (jj == i) lam = a[i];
    return lam;
}

// ---------------- K0: zero atomic accumulators ----------------
__global__ void k0_zero(float* ws) {
    int tid = threadIdx.x;
    for (int i = tid; i < 352; i += 256) ws[i] = 0.f;
}

// ---------------- K1: x channel sums + Gram (for analytic BN1) ----------------
__global__ __launch_bounds__(256) void k1_stats(const float* __restrict__ x,
                                                float* __restrict__ sumx,
                                                float* __restrict__ G) {
    int b = blockIdx.x, tid = threadIdx.x;
    __shared__ float xt[22 * 257];
    float accp = 0.f, accs = 0.f;
    int c1 = 0, c2 = 0;
    if (tid < 253) { c1 = T22.a[tid]; c2 = T22.b[tid]; }
    const float* xb = x + (size_t)b * 22 * 2047;
    for (int t0 = 0; t0 < 2047; t0 += 256) {
        __syncthreads();
        for (int idx = tid; idx < 22 * 256; idx += 256) {
            int c = idx >> 8, tl = idx & 255;
            int t = t0 + tl;
            xt[c * 257 + tl] = (t < 2047) ? xb[c * 2047 + t] : 0.f;
        }
        __syncthreads();
        if (tid < 253) {
            float s = 0.f;
            for (int t = 0; t < 256; ++t) s += xt[c1 * 257 + t] * xt[c2 * 257 + t];
            accp += s;
        }
        if (tid < 22) {
            float s = 0.f;
            for (int t = 0; t < 256; ++t) s += xt[tid * 257 + t];
            accs += s;
        }
    }
    if (tid < 253) atomicAdd(&G[tid], accp);
    if (tid < 22) atomicAdd(&sumx[tid], accs);
}

// ---------------- K2: finalize BN1 -> A = diag(s1)W, d; reorder w_temp ----------------
__global__ __launch_bounds__(256) void k2_prep(const float* __restrict__ w_spat,
                                               const float* __restrict__ b_spat,
                                               const float* __restrict__ g1,
                                               const float* __restrict__ be1,
                                               const float* __restrict__ w_temp,
                                               const float* __restrict__ sumx,
                                               const float* __restrict__ G,
                                               float* __restrict__ A,
                                               float* __restrict__ dv,
                                               float* __restrict__ w_r) {
    int tid = threadIdx.x;
    __shared__ float cov[22 * 22], mux[22], mu1s[22], s1s[22];
    const float invN = 1.f / (1024.f * 2047.f);
    if (tid < 22) mux[tid] = sumx[tid] * invN;
    __syncthreads();
    if (tid < 253) {
        int c1 = T22.a[tid], c2 = T22.b[tid];
        float cv = G[tid] * invN - mux[c1] * mux[c2];
        cov[c1 * 22 + c2] = cv; cov[c2 * 22 + c1] = cv;
    }
    __syncthreads();
    if (tid < 22) {
        int c = tid;
        float m = b_spat[c], varv = 0.f;
        for (int e = 0; e < 22; ++e) m += w_spat[c * 22 + e] * mux[e];
        for (int i = 0; i < 22; ++i) {
            float wi = w_spat[c * 22 + i];
            for (int j = 0; j < 22; ++j) varv += wi * w_spat[c * 22 + j] * cov[i * 22 + j];
        }
        mu1s[c] = m;
        s1s[c] = g1[c] * rsqrtf(varv + 1e-5f);
    }
    __syncthreads();
    for (int idx = tid; idx < 484; idx += 256) {
        int c = idx / 22;
        A[idx] = s1s[c] * w_spat[idx];
    }
    if (tid < 22) dv[tid] = s1s[tid] * (b_spat[tid] - mu1s[tid]) + be1[tid];
    // w_r[(c*12+k)*20 + f] = w_temp[f][c][k]
    for (int idx = tid; idx < 5280; idx += 256) {
        int f = idx / 264, r = idx % 264;
        w_r[r * 20 + f] = w_temp[idx];
    }
}

// ---------------- K3: fused (spatial+BN1) -> temporal conv -> patch raw cov + BN2 stats ----------------
__global__ __launch_bounds__(256) void k3_conv(const float* __restrict__ x,
                                               const float* __restrict__ wsA,
                                               const float* __restrict__ wsd,
                                               const float* __restrict__ w_r,
                                               float* __restrict__ cov_raw,
                                               float* __restrict__ sum2,
                                               float* __restrict__ sumsq2) {
    int bp = blockIdx.x;           // b*8 + p
    int b = bp >> 3, p = bp & 7;
    int tid = threadIdx.x;
    __shared__ float xs[22 * 267];  // x tile, then conv-input (A x + d, zero-padded) in place
    __shared__ float h2[20 * 257];  // conv output tile (b_temp dropped: shift-invariant)
    __shared__ float pm[20];

    const float* xb = x + (size_t)b * 22 * 2047;
    const int t0 = p * 256 - 6;
    for (int idx = tid; idx < 22 * 267; idx += 256) {
        int c = idx / 267, tl = idx % 267;
        int t = t0 + tl;
        xs[idx] = (t >= 0 && t < 2047) ? xb[c * 2047 + t] : 0.f;
    }
    __syncthreads();
    // conv input in place: column per thread
    for (int tl = tid; tl < 267; tl += 256) {
        float xv[22];
#pragma unroll
        for (int c = 0; c < 22; ++c) xv[c] = xs[c * 267 + tl];
        int t = t0 + tl;
        bool valid = (t >= 0 && t < 2047);
#pragma unroll
        for (int c = 0; c < 22; ++c) {
            float acc = wsd[c];
#pragma unroll
            for (int e = 0; e < 22; ++e) acc += wsA[c * 22 + e] * xv[e];
            xs[c * 267 + tl] = valid ? acc : 0.f;
        }
    }
    __syncthreads();
    // temporal conv: thread = output column
    {
        int tl = tid;
        float acc[20];
#pragma unroll
        for (int f = 0; f < 20; ++f) acc[f] = 0.f;
        for (int c = 0; c < 22; ++c) {
#pragma unroll
            for (int k = 0; k < 12; ++k) {
                float hv = xs[c * 267 + tl + k];
                const float* wp = w_r + (c * 12 + k) * 20;   // wave-uniform -> s_load
#pragma unroll
                for (int f = 0; f < 20; ++f) acc[f] += wp[f] * hv;
            }
        }
#pragma unroll
        for (int f = 0; f < 20; ++f) h2[f * 257 + tl] = acc[f];
    }
    __syncthreads();
    // per-patch means + global BN2 accumulators
    if (tid < 20) {
        int f = tid;
        float s = 0.f, ss = 0.f;
        for (int t = 0; t < 256; ++t) { float v = h2[f * 257 + t]; s += v; ss += v * v; }
        pm[f] = s * (1.f / 256.f);
        atomicAdd(&sum2[f], s);
        atomicAdd(&sumsq2[f], ss);
    }
    __syncthreads();
    // raw patch covariance (unnormalized; trace-norm cancels divisors downstream)
    for (int pr = tid; pr < 210; pr += 256) {
        int f = T20.a[pr], g = T20.b[pr];
        float s = 0.f;
        for (int t = 0; t < 256; ++t) s += h2[f * 257 + t] * h2[g * 257 + t];
        float cv = s - 256.f * pm[f] * pm[g];
        cov_raw[(size_t)bp * 400 + f * 20 + g] = cv;
        if (f != g) cov_raw[(size_t)bp * 400 + g * 20 + f] = cv;
    }
}

// ---------------- K4: finalize BN2 scale ----------------
__global__ void k4_s2(const float* __restrict__ g2, const float* __restrict__ sum2,
                      const float* __restrict__ sumsq2, float* __restrict__ s2) {
    int tid = threadIdx.x;
    if (tid < 20) {
        const float invN = 1.f / (1024.f * 2048.f);
        float mu = sum2[tid] * invN;
        float var = sumsq2[tid] * invN - mu * mu;
        s2[tid] = g2[tid] * rsqrtf(var + 1e-5f);
    }
}

// ---------------- K5: BiMap Q/K/V (s2 folded into W), eigh, logm ----------------
// 4 waves per block, one bp per wave (round-0 proven layout, V stored as
// columns; natural register allocation).
__global__ __launch_bounds__(256) void k5_qkv(const float* __restrict__ wq,
                                              const float* __restrict__ wk,
                                              const float* __restrict__ wv,
                                              const float* __restrict__ s2g,
                                              const float* __restrict__ cov_raw,
                                              float* __restrict__ lqkv) {
    int tid = threadIdx.x;
    int wave = tid >> 6;
    int lane = tid & 63;
    int bp = blockIdx.x * 4 + wave;
    __shared__ float Wl[1080];       // [m][18][20], pre-scaled by s2[e] (shared)
    __shared__ float s2l[20];
    __shared__ float covn[4][400];   // per-wave raw patch covariance
    __shared__ float Vs[4][972];
    __shared__ float lws[4][54];

    if (tid < 20) s2l[tid] = s2g[tid];
    for (int idx = lane; idx < 400; idx += 64)
        covn[wave][idx] = cov_raw[(size_t)bp * 400 + idx];
    __syncthreads();
    for (int idx = tid; idx < 1080; idx += 256) {
        int m = idx / 360, rem = idx % 360;
        const float* W = (m == 0) ? wq : (m == 1) ? wk : wv;
        Wl[idx] = W[rem] * s2l[rem % 20];
    }
    __syncthreads();

    // trace of s2-scaled cov (broadcast LDS reads, every lane redundantly)
    float tr = 0.f;
#pragma unroll
    for (int f = 0; f < 20; ++f) tr += covn[wave][f * 21] * s2l[f] * s2l[f];
    float trinv = 1.f / tr;

    int grp = lane / 18;
    int jj = lane - grp * 18;
    int m = grp < 3 ? grp : 2;
    int base = grp * 18;
    // Wrow = scaled W_m row jj
    float Wrow[20];
#pragma unroll
    for (int d = 0; d < 20; ++d) Wrow[d] = Wl[m * 360 + jj * 20 + d];
    // u[e] = sum_d covn[e][d] * Wrow[d]  (covn symmetric)
    float u[20];
#pragma unroll
    for (int e = 0; e < 20; ++e) {
        float acc = 0.f;
#pragma unroll
        for (int d = 0; d < 20; ++d) acc += covn[wave][e * 20 + d] * Wrow[d];
        u[e] = acc;
    }
    // a[i] = trinv * sum_e Wl[m][i][e] * u[e]
    float a[18], v[18];
#pragma unroll
    for (int i = 0; i < 18; ++i) {
        float acc = 0.f;
#pragma unroll
        for (int e = 0; e < 20; ++e) acc += Wl[m * 360 + i * 20 + e] * u[e];
        a[i] = acc * trinv;
        v[i] = (i == jj) ? 1.f : 0.f;
    }
    float lam = jacobi18(a, v, jj, base);
    float lw = __logf(fmaxf(lam, 1e-10f));
    if (grp < 3) {
#pragma unroll
        for (int i = 0; i < 18; ++i) Vs[wave][(m * 18 + i) * 18 + jj] = v[i];
        lws[wave][m * 18 + jj] = lw;
    }
    __builtin_amdgcn_wave_barrier();   // wave-synchronous LDS: write->read same wave
    // L = V diag(lw) V^T, write lq/lk/lv
    for (int idx = lane; idx < 972; idx += 64) {
        int m2 = idx / 324, rem = idx % 324, i = rem / 18, jo = rem % 18;
        float acc = 0.f;
#pragma unroll
        for (int kk = 0; kk < 18; ++kk)
            acc += Vs[wave][(m2 * 18 + i) * 18 + kk] * lws[wave][m2 * 18 + kk] * Vs[wave][(m2 * 18 + jo) * 18 + kk];
        lqkv[(size_t)(bp * 3 + m2) * 324 + rem] = acc;
    }
}

// ---------------- K6: log-Euclidean attention -> mixed tangent matrices ----------------
__global__ __launch_bounds__(256) void k6_attn(const float* __restrict__ lqkv,
                                               float* __restrict__ mixed) {
    int b = blockIdx.x, tid = threadIdx.x;
    __shared__ float L[7776];       // [p][m][324]
    __shared__ float sq[8], sk[8], cross[64], prob[64];
    const float* src = lqkv + (size_t)b * 7776;
    for (int idx = tid; idx < 7776; idx += 256) L[idx] = src[idx];
    __syncthreads();
    if (tid < 64) {
        int i = tid >> 3, j = tid & 7;
        const float* fq = &L[(i * 3 + 0) * 324];
        const float* fk = &L[(j * 3 + 1) * 324];
        float cr = 0.f;
        for (int e = 0; e < 324; ++e) cr += fq[e] * fk[e];
        cross[tid] = cr;
    } else if (tid < 72) {
        int i = tid - 64;
        const float* fq = &L[(i * 3 + 0) * 324];
        float s = 0.f;
        for (int e = 0; e < 324; ++e) s += fq[e] * fq[e];
        sq[i] = s;
    } else if (tid < 80) {
        int i = tid - 72;
        const float* fk = &L[(i * 3 + 1) * 324];
        float s = 0.f;
        for (int e = 0; e < 324; ++e) s += fk[e] * fk[e];
        sk[i] = s;
    }
    __syncthreads();
    if (tid < 8) {
        int j = tid;
        float w[8], mx = -1e30f;
        for (int i = 0; i < 8; ++i) {
            float d2 = fmaxf(sq[i] + sk[j] - 2.f * cross[i * 8 + j], 0.0f);
            float en = sqrtf(d2 + 1e-12f);
            w[i] = 1.f / (1.f + log1pf(en));
            mx = fmaxf(mx, w[i]);
        }
        float ssum = 0.f;
        for (int i = 0; i < 8; ++i) { w[i] = __expf(w[i] - mx); ssum += w[i]; }
        float inv = 1.f / ssum;
        for (int i = 0; i < 8; ++i) prob[i * 8 + j] = w[i] * inv;
    }
    __syncthreads();
    float* dst = mixed + (size_t)b * 8 * 324;
    for (int idx = tid; idx < 8 * 324; idx += 256) {
        int j = idx / 324, e = idx % 324;
        float acc = 0.f;
#pragma unroll
        for (int i = 0; i < 8; ++i) acc += prob[i * 8 + j] * L[(i * 3 + 2) * 324 + e];
        dst[idx] = acc;
    }
}

// ---------------- K7: eigh(mixed) -> clamp eigs -> triu vec, Gershgorin fast path ----------------
// 4 waves per block, 3 matrices per wave (12 per block). NO __syncthreads:
// all sync is wave-local (shfl reduce + wave-synchronous LDS slices), so the
// per-wave divergent Gershgorin skip is barrier-safe.
__global__ __launch_bounds__(256) void k7_post(const float* __restrict__ mixed,
                                               float* __restrict__ feat) {
    int tid = threadIdx.x;
    int wave = tid >> 6;
    int lane = tid & 63;
    int blk = blockIdx.x;
    int grp = lane / 18;
    int jj = lane - grp * 18;
    int m = grp < 3 ? grp : 2;
    int base = grp * 18;
    int mat = blk * 12 + wave * 3 + m;
    int matc = mat < 8192 ? mat : 8191;
    __shared__ float Vs[4][972];
    __shared__ float lws[4][54];

    const float* src = mixed + (size_t)matc * 324;
    float a[18], v[18];
#pragma unroll
    for (int i = 0; i < 18; ++i) {
        a[i] = src[i * 18 + jj];
        v[i] = (i == jj) ? 1.f : 0.f;
    }
    // Gershgorin lower bound for this column: diag - sum_{i!=jj}|a[i]| = 2*diag - sum|a[i]|
    float diag = a[0], asum = 0.f;
#pragma unroll
    for (int i = 0; i < 18; ++i) {
        if (jj == i) diag = a[i];
        asum += fabsf(a[i]);
    }
    float gb = 2.f * diag - asum;    // lanes 54..63 hold a duplicate of m=2: harmless
    // wave-min butterfly
#pragma unroll
    for (int off = 32; off; off >>= 1) gb = fminf(gb, __shfl_xor(gb, off, 64));
    const bool skipAll = (gb > -9.2103f);   // wave-uniform; clamp is a no-op -> lt == M

    if (!skipAll) {
        float lam = jacobi18(a, v, jj, base);
        float lw = fmaxf(lam, -9.210340371976182f);   // ln(1e-4)
        if (grp < 3) {
#pragma unroll
            for (int i = 0; i < 18; ++i) Vs[wave][(m * 18 + i) * 18 + jj] = v[i];
            lws[wave][m * 18 + jj] = lw;
        }
    }
    __builtin_amdgcn_wave_barrier();   // wave-synchronous LDS slice
    for (int idx = lane; idx < 513; idx += 64) {
        int m2 = idx / 171, rem = idx % 171;
        int mat2 = blk * 12 + wave * 3 + m2;
        if (mat2 >= 8192) continue;
        int i = T18.a[rem], jo = T18.b[rem];
        float acc;
        if (skipAll) {
            acc = mixed[(size_t)mat2 * 324 + i * 18 + jo];   // lt == M exactly
        } else {
            acc = 0.f;
#pragma unroll
            for (int kk = 0; kk < 18; ++kk)
                acc += Vs[wave][(m2 * 18 + i) * 18 + kk] * lws[wave][m2 * 18 + kk] * Vs[wave][(m2 * 18 + jo) * 18 + kk];
        }
        float scl = (i == jo) ? 1.f : 1.41421356237309515f;
        int bb = mat2 >> 3, pp = mat2 & 7;
        feat[(size_t)bb * 1368 + pp * 171 + rem] = acc * scl;
    }
}

// ---------------- K8: final linear ----------------
__global__ __launch_bounds__(256) void k8_lin(const float* __restrict__ feat,
                                              const float* __restrict__ w_lin,
                                              const float* __restrict__ b_lin,
                                              float* __restrict__ out) {
    int b = blockIdx.x, tid = threadIdx.x;
    int o = tid >> 6, lane = tid & 63;
    const float* fb = feat + (size_t)b * 1368;
    const float* wo = w_lin + o * 1368;
    float acc = 0.f;
    for (int e = lane; e < 1368; e += 64) acc += fb[e] * wo[e];
    for (int off = 32; off; off >>= 1) acc += __shfl_down(acc, off, 64);
    if (lane == 0) out[b * 4 + o] = acc + b_lin[o];
}

// ---------------- launcher ----------------
extern "C" void kernel_launch(void* const* d_in, const int* in_sizes, int n_in,
                              void* d_out, int out_size, void* d_ws, size_t ws_size,
                              hipStream_t stream) {
    (void)in_sizes; (void)n_in; (void)out_size; (void)ws_size;
    const float* x      = (const float*)d_in[0];
    const float* w_spat = (const float*)d_in[1];
    const float* b_spat = (const float*)d_in[2];
    const float* g1     = (const float*)d_in[3];
    const float* be1    = (const float*)d_in[4];
    const float* w_temp = (const float*)d_in[5];
    // d_in[6] = b_temp : cancels in patch covariance -> unused
    const float* g2     = (const float*)d_in[7];
    // d_in[8] = be2 : cancels -> unused
    const float* wq     = (const float*)d_in[9];
    const float* wk     = (const float*)d_in[10];
    const float* wv     = (const float*)d_in[11];
    const float* w_lin  = (const float*)d_in[12];
    const float* b_lin  = (const float*)d_in[13];
    float* ws  = (float*)d_ws;
    float* out = (float*)d_out;

    k0_zero<<<1, 256, 0, stream>>>(ws);
    k1_stats<<<1024, 256, 0, stream>>>(x, ws + OFF_SUMX, ws + OFF_G);
    k2_prep<<<1, 256, 0, stream>>>(w_spat, b_spat, g1, be1, w_temp,
                                   ws + OFF_SUMX, ws + OFF_G,
                                   ws + OFF_A, ws + OFF_D, ws + OFF_WR);
    k3_conv<<<8192, 256, 0, stream>>>(x, ws + OFF_A, ws + OFF_D, ws + OFF_WR,
                                      ws + OFF_COV, ws + OFF_SUM2, ws + OFF_SUMSQ2);
    k4_s2<<<1, 64, 0, stream>>>(g2, ws + OFF_SUM2, ws + OFF_SUMSQ2, ws + OFF_S2);
    k5_qkv<<<2048, 256, 0, stream>>>(wq, wk, wv, ws + OFF_S2, ws + OFF_COV, ws + OFF_LQKV);
    k6_attn<<<1024, 256, 0, stream>>>(ws + OFF_LQKV, ws + OFF_COV /* mixed reuses cov region */);
    k7_post<<<683, 256, 0, stream>>>(ws + OFF_COV, ws + OFF_FEAT);
    k8_lin<<<1024, 256, 0, stream>>>(ws + OFF_FEAT, w_lin, b_lin, out);
}

// Round 11
// 1437.086 us; speedup vs baseline: 1.2488x; 1.1021x over previous
//
#include <hip/hip_runtime.h>
#include <math.h>

// ---------------- problem constants ----------------
// Sweep history: 8,6,5 sweeps all bit-identical absmax 0.0078125 (=2^-7, the
// bf16 output floor). 4 sweeps (68 rounds): absmax 0.03125 -> FAILED threshold
// 0.0311 by 0.5%. Quadratic convergence + the tiny failure margin -> half a
// sweep more should suffice: 4 full sweeps + 9 rounds = 77 rounds.
constexpr int FULL_SWEEPS  = 4;
constexpr int EXTRA_ROUNDS = 9;

// ws offsets (in floats)
constexpr size_t OFF_SUMX   = 0;        // 22
constexpr size_t OFF_G      = 22;       // 253
constexpr size_t OFF_SUM2   = 288;      // 20
constexpr size_t OFF_SUMSQ2 = 308;      // 20
constexpr size_t OFF_S2     = 328;      // 20
constexpr size_t OFF_WD     = 352;      // 240  (was A; merged-conv d-term table)
constexpr size_t OFF_WDSUM  = 840;      // 20   (was D; interior d-term row sums)
constexpr size_t OFF_MW     = 864;      // 5280 (was WR; merged spatial+temporal weights)
constexpr size_t OFF_COV    = 6144;     // 8192*400 (later reused as `mixed` 8192*324)
constexpr size_t OFF_LQKV   = 3282944;  // 8192*3*324
constexpr size_t OFF_FEAT   = 11245568; // 1024*1368

// ---------------- constexpr tables ----------------
struct Tri { int a[253]; int b[253]; };
constexpr Tri mk_tri(int n) {
    Tri t{}; int c = 0;
    for (int i = 0; i < n; ++i) for (int j = i; j < n; ++j) { t.a[c] = i; t.b[c] = j; ++c; }
    return t;
}
constexpr Tri T22 = mk_tri(22);
constexpr Tri T20 = mk_tri(20);
constexpr Tri T18 = mk_tri(18);

// round-robin (circle method) schedule for n=18: 17 rounds x 9 disjoint pairs, p<q
struct Sched { int p[17][9]; int q[17][9]; };
constexpr Sched mk_sched() {
    Sched s{};
    for (int r = 0; r < 17; ++r)
        for (int k = 0; k < 9; ++k) {
            int x, y;
            if (k == 0) { x = 17; y = r; }
            else { x = (r + k) % 17; y = (r - k + 17) % 17; }
            s.p[r][k] = x < y ? x : y;
            s.q[r][k] = x < y ? y : x;
        }
    return s;
}
constexpr Sched SCH = mk_sched();

// ---------------- wave-parallel 18x18 Jacobi eigh (v8 structure, HW-proven best) ----------------
// Lane (within wave) = base + jj holds column jj (a[i] = A[i][jj]; v[i] = V[i][jj]).
// 3 matrices per wave (bases 0,18,36); lanes 54..63 run an isolated duplicate
// of group 2 (shfl only pulls, so they never contaminate groups 0-2).
//
// TEN-ROUND CONCLUSION (all structural variants bit-identical absmax):
//   v8 (this structure):                    96 VGPR, 556us @5 sweeps <- best
//   v1 (kt-select instead of mt-shfl):      104 VGPR, 612us
//   v4/v6 (V-as-rows, fewer DS/round):      136 VGPR, 697-767us (128-cliff)
//   v7 (v6 + per-round sched_barrier):      104 VGPR, 718us (serialized)
//   v3/v5 (rsq inlined in row loop):        256 VGPR + GB-scale spills
// k5 is DS(bpermute)-throughput bound; the V-column exchange doubles as the
// latency filler overlapping the next round's serial head. Do not remove it,
// do not fence rounds, do not inline the rsq. Round count is the proportional
// lever: 68 rounds failed absmax by 0.5%, 85 is floor-converged -> try 77.
//
// CORRECTNESS INVARIANT: every lane of a pair applies the bitwise-IDENTICAL
// (c,s) in BOTH the row and the column update (p-lane tangent broadcast +
// redundant identical recompute). mt = shfl(t0, base+plane) reads the SAME
// source lane as the tb[] entry for my pair -> identical bits.
__device__ __forceinline__ float jacobi18(float* __restrict__ a, float* __restrict__ v,
                                          int jj, int base) {
    // per-round partner table (depends only on (r, jj)) — compute once
    int pt[17];
#pragma unroll
    for (int r = 0; r < 17; ++r) {
        int k1 = jj - r; if (k1 < 0) k1 += 17;
        int partner;
        if (jj == 17)      { partner = r; }
        else if (k1 == 0)  { partner = 17; }
        else if (k1 <= 8)  { partner = r - k1; if (partner < 0) partner += 17; }
        else               { partner = r + 17 - k1; if (partner >= 17) partner -= 17; }
        pt[r] = partner;
    }
    // own diagonal, maintained analytically (rotation decisions only; final
    // eigenvalue read from the true stored a[jj])
    float mydiag = a[0];
#pragma unroll
    for (int i = 1; i < 18; ++i) if (jj == i) mydiag = a[i];

    auto round_body = [&](int r) {
        const int partner = pt[r];
        const int paddr = base + partner;
        const bool isp = jj < partner;
        const int plane = isp ? jj : partner;   // p-lane (min) of my pair
        // partner's diagonal (1 shfl)
        float pd = __shfl(mydiag, paddr, 64);
        // own off-diagonal apq = a[partner] (18-way select, partner lane-varying)
        float apq = a[0];
#pragma unroll
        for (int i = 1; i < 18; ++i) if (partner == i) apq = a[i];
        float app = isp ? mydiag : pd;
        float aqq = isp ? pd : mydiag;
        // candidate tangent (only the p-lane's version gets used)
        float apqc = (fabsf(apq) < 1e-36f) ? 1e-36f : apq;
        float tau = (aqq - app) * 0.5f * __builtin_amdgcn_rcpf(apqc);
        float t0 = __builtin_amdgcn_rcpf(fabsf(tau) + __builtin_amdgcn_sqrtf(fmaf(tau, tau, 1.f)));
        t0 = (tau < 0.f) ? -t0 : t0;
        // broadcast the 9 pair tangents from p-lanes + my own pair's tangent
        float tb[9];
#pragma unroll
        for (int k = 0; k < 9; ++k)
            tb[k] = __shfl(t0, base + SCH.p[r][k], 64);
        float mt = __shfl(t0, base + plane, 64);
        // recompute (c,s) locally — bitwise identical in every lane
        float cc[9], ss[9];
#pragma unroll
        for (int k = 0; k < 9; ++k) {
            cc[k] = __builtin_amdgcn_rsqf(fmaf(tb[k], tb[k], 1.f));
            ss[k] = tb[k] * cc[k];
        }
        // my pair's (c,s): identical expression + identical input bits
        float mc = __builtin_amdgcn_rsqf(fmaf(mt, mt, 1.f));
        float ms = mt * mc;
        // analytic diagonal update
        mydiag = fmaf(isp ? -mt : mt, apq, mydiag);
        // row update (lane-local registers), all 9 disjoint pairs
#pragma unroll
        for (int k = 0; k < 9; ++k) {
            const int p = SCH.p[r][k], q = SCH.q[r][k];
            float tp = a[p], tq = a[q];
            a[p] = cc[k] * tp - ss[k] * tq;
            a[q] = ss[k] * tp + cc[k] * tq;
        }
        // column update with the SAME uniform (mc,ms) via partner exchange.
        // A and V exchanges are the latency filler — keep them.
        float ssig = isp ? -ms : ms;
#pragma unroll
        for (int i = 0; i < 18; ++i) {
            float oa = __shfl(a[i], paddr, 64);
            a[i] = mc * a[i] + ssig * oa;
        }
#pragma unroll
        for (int i = 0; i < 18; ++i) {
            float ov = __shfl(v[i], paddr, 64);
            v[i] = mc * v[i] + ssig * ov;
        }
    };

    for (int sw = 0; sw < FULL_SWEEPS; ++sw) {
#pragma unroll
        for (int r = 0; r < 17; ++r) round_body(r);
    }
#pragma unroll
    for (int r = 0; r < EXTRA_ROUNDS; ++r) round_body(r);

    // eigenvalue = true stored diagonal (no analytic drift)
    float lam = a[0];
#pragma unroll
    for (int i = 1; i < 18; ++i) if (jj == i) lam = a[i];
    return lam;
}

// ---------------- K0: zero atomic accumulators ----------------
__global__ void k0_zero(float* ws) {
    int tid = threadIdx.x;
    for (int i = tid; i < 352; i += 256) ws[i] = 0.f;
}

// ---------------- K1: x channel sums + Gram (for analytic BN1) ----------------
__global__ __launch_bounds__(256) void k1_stats(const float* __restrict__ x,
                                                float* __restrict__ sumx,
                                                float* __restrict__ G) {
    int b = blockIdx.x, tid = threadIdx.x;
    __shared__ float xt[22 * 257];
    float accp = 0.f, accs = 0.f;
    int c1 = 0, c2 = 0;
    if (tid < 253) { c1 = T22.a[tid]; c2 = T22.b[tid]; }
    const float* xb = x + (size_t)b * 22 * 2047;
    for (int t0 = 0; t0 < 2047; t0 += 256) {
        __syncthreads();
        for (int idx = tid; idx < 22 * 256; idx += 256) {
            int c = idx >> 8, tl = idx & 255;
            int t = t0 + tl;
            xt[c * 257 + tl] = (t < 2047) ? xb[c * 2047 + t] : 0.f;
        }
        __syncthreads();
        if (tid < 253) {
            float s = 0.f;
            for (int t = 0; t < 256; ++t) s += xt[c1 * 257 + t] * xt[c2 * 257 + t];
            accp += s;
        }
        if (tid < 22) {
            float s = 0.f;
            for (int t = 0; t < 256; ++t) s += xt[tid * 257 + t];
            accs += s;
        }
    }
    if (tid < 253) atomicAdd(&G[tid], accp);
    if (tid < 22) atomicAdd(&sumx[tid], accs);
}

// ---------------- K2: finalize BN1; build MERGED conv weights ----------------
// Merged conv derivation (exact up to fp32 reassociation):
//   ci[c,t] = valid(t) ? (sum_e A[c,e] x[e,t] + d[c]) : 0, A = diag(s1)W_spat
//   h2[f,t] = sum_{c,k} wr[c,k,f] ci[c,t+k]
//           = sum_{e,k} Mw[(e,k),f] x~[e,t+k]  +  sum_{k valid} wd[k,f]
//   where Mw[(e,k),f] = sum_c wr[c,k,f] A[c,e],  wd[k,f] = sum_c wr[c,k,f] d[c],
//   x~ zero-padded (the A-term vanishes automatically at invalid taps).
// Interior columns (all 12 taps valid) add wdsum[f] = sum_k wd[k,f] once.
__global__ __launch_bounds__(256) void k2_prep(const float* __restrict__ w_spat,
                                               const float* __restrict__ b_spat,
                                               const float* __restrict__ g1,
                                               const float* __restrict__ be1,
                                               const float* __restrict__ w_temp,
                                               const float* __restrict__ sumx,
                                               const float* __restrict__ G,
                                               float* __restrict__ Mw,
                                               float* __restrict__ wd,
                                               float* __restrict__ wdsum) {
    int tid = threadIdx.x;
    __shared__ float cov[22 * 22], mux[22], mu1s[22], s1s[22], dvs[22];
    __shared__ float As[484];
    const float invN = 1.f / (1024.f * 2047.f);
    if (tid < 22) mux[tid] = sumx[tid] * invN;
    __syncthreads();
    if (tid < 253) {
        int c1 = T22.a[tid], c2 = T22.b[tid];
        float cv = G[tid] * invN - mux[c1] * mux[c2];
        cov[c1 * 22 + c2] = cv; cov[c2 * 22 + c1] = cv;
    }
    __syncthreads();
    if (tid < 22) {
        int c = tid;
        float m = b_spat[c], varv = 0.f;
        for (int e = 0; e < 22; ++e) m += w_spat[c * 22 + e] * mux[e];
        for (int i = 0; i < 22; ++i) {
            float wi = w_spat[c * 22 + i];
            for (int j = 0; j < 22; ++j) varv += wi * w_spat[c * 22 + j] * cov[i * 22 + j];
        }
        mu1s[c] = m;
        s1s[c] = g1[c] * rsqrtf(varv + 1e-5f);
    }
    __syncthreads();
    for (int idx = tid; idx < 484; idx += 256) {
        int c = idx / 22;
        As[idx] = s1s[c] * w_spat[idx];
    }
    if (tid < 22) dvs[tid] = s1s[tid] * (b_spat[tid] - mu1s[tid]) + be1[tid];
    __syncthreads();
    // Mw[(e*12+k)*20+f] = sum_c w_temp[f*264 + c*12 + k] * As[c*22+e]
    for (int idx = tid; idx < 5280; idx += 256) {
        int r = idx / 20, f = idx % 20;
        int e = r / 12, k = r % 12;
        float acc = 0.f;
        for (int c = 0; c < 22; ++c)
            acc += w_temp[f * 264 + c * 12 + k] * As[c * 22 + e];
        Mw[idx] = acc;
    }
    // wd[k*20+f] = sum_c w_temp[f*264+c*12+k] * dvs[c];  wdsum[f] = sum_k wd
    if (tid < 240) {
        int k = tid / 20, f = tid % 20;
        float acc = 0.f;
        for (int c = 0; c < 22; ++c)
            acc += w_temp[f * 264 + c * 12 + k] * dvs[c];
        wd[tid] = acc;
    } else if (tid < 260) {
        int f = tid - 240;
        float acc = 0.f;
        for (int k = 0; k < 12; ++k)
            for (int c = 0; c < 22; ++c)
                acc += w_temp[f * 264 + c * 12 + k] * dvs[c];
        wdsum[f] = acc;
    }
}

// ---------------- K3: merged (spatial+BN1+temporal) conv -> patch raw cov + BN2 stats ----------------
__global__ __launch_bounds__(256) void k3_conv(const float* __restrict__ x,
                                               const float* __restrict__ Mw,
                                               const float* __restrict__ wd,
                                               const float* __restrict__ wdsum,
                                               float* __restrict__ cov_raw,
                                               float* __restrict__ sum2,
                                               float* __restrict__ sumsq2) {
    int bp = blockIdx.x;           // b*8 + p
    int b = bp >> 3, p = bp & 7;
    int tid = threadIdx.x;
    __shared__ float xs[22 * 267];  // raw x tile, zero-padded
    __shared__ float h2[20 * 257];  // conv output tile (b_temp dropped: shift-invariant)
    __shared__ float pm[20];

    const float* xb = x + (size_t)b * 22 * 2047;
    const int t0 = p * 256 - 6;
    for (int idx = tid; idx < 22 * 267; idx += 256) {
        int c = idx / 267, tl = idx % 267;
        int t = t0 + tl;
        xs[idx] = (t >= 0 && t < 2047) ? xb[c * 2047 + t] : 0.f;
    }
    __syncthreads();
    // merged conv: thread = output column (the spatial phase is folded into Mw)
    {
        int tl = tid;
        float acc[20];
#pragma unroll
        for (int f = 0; f < 20; ++f) acc[f] = 0.f;
        for (int e = 0; e < 22; ++e) {
#pragma unroll
            for (int k = 0; k < 12; ++k) {
                float hv = xs[e * 267 + tl + k];
                const float* wp = Mw + (e * 12 + k) * 20;   // wave-uniform -> s_load
#pragma unroll
                for (int f = 0; f < 20; ++f) acc[f] += wp[f] * hv;
            }
        }
        // d-term: exact at sequence edges (taps outside [0,2047) contribute no d)
        int tcol = t0 + tl;
        if (tcol >= 0 && tcol + 11 < 2047) {
#pragma unroll
            for (int f = 0; f < 20; ++f) acc[f] += wdsum[f];
        } else {
#pragma unroll
            for (int k = 0; k < 12; ++k) {
                int t = tcol + k;
                float vm = (t >= 0 && t < 2047) ? 1.f : 0.f;
                const float* wdp = wd + k * 20;
#pragma unroll
                for (int f = 0; f < 20; ++f) acc[f] = fmaf(vm, wdp[f], acc[f]);
            }
        }
#pragma unroll
        for (int f = 0; f < 20; ++f) h2[f * 257 + tl] = acc[f];
    }
    __syncthreads();
    // per-patch means + global BN2 accumulators
    if (tid < 20) {
        int f = tid;
        float s = 0.f, ss = 0.f;
        for (int t = 0; t < 256; ++t) { float v = h2[f * 257 + t]; s += v; ss += v * v; }
        pm[f] = s * (1.f / 256.f);
        atomicAdd(&sum2[f], s);
        atomicAdd(&sumsq2[f], ss);
    }
    __syncthreads();
    // raw patch covariance (unnormalized; trace-norm cancels divisors downstream)
    for (int pr = tid; pr < 210; pr += 256) {
        int f = T20.a[pr], g = T20.b[pr];
        float s = 0.f;
        for (int t = 0; t < 256; ++t) s += h2[f * 257 + t] * h2[g * 257 + t];
        float cv = s - 256.f * pm[f] * pm[g];
        cov_raw[(size_t)bp * 400 + f * 20 + g] = cv;
        if (f != g) cov_raw[(size_t)bp * 400 + g * 20 + f] = cv;
    }
}

// ---------------- K4: finalize BN2 scale ----------------
__global__ void k4_s2(const float* __restrict__ g2, const float* __restrict__ sum2,
                      const float* __restrict__ sumsq2, float* __restrict__ s2) {
    int tid = threadIdx.x;
    if (tid < 20) {
        const float invN = 1.f / (1024.f * 2048.f);
        float mu = sum2[tid] * invN;
        float var = sumsq2[tid] * invN - mu * mu;
        s2[tid] = g2[tid] * rsqrtf(var + 1e-5f);
    }
}

// ---------------- K5: BiMap Q/K/V (s2 folded into W), eigh, logm ----------------
// 4 waves per block, one bp per wave (v8-proven layout, V stored as columns;
// natural register allocation: 96 VGPR, no spills). Epilogue computes only
// the 513 triu entries and mirrors (L symmetric; acc expression symmetric in
// (i,jo) with identical k-order -> bitwise identical to computing both).
__global__ __launch_bounds__(256) void k5_qkv(const float* __restrict__ wq,
                                              const float* __restrict__ wk,
                                              const float* __restrict__ wv,
                                              const float* __restrict__ s2g,
                                              const float* __restrict__ cov_raw,
                                              float* __restrict__ lqkv) {
    int tid = threadIdx.x;
    int wave = tid >> 6;
    int lane = tid & 63;
    int bp = blockIdx.x * 4 + wave;
    __shared__ float Wl[1080];       // [m][18][20], pre-scaled by s2[e] (shared)
    __shared__ float s2l[20];
    __shared__ float covn[4][400];   // per-wave raw patch covariance
    __shared__ float Vs[4][972];
    __shared__ float lws[4][54];

    if (tid < 20) s2l[tid] = s2g[tid];
    for (int idx = lane; idx < 400; idx += 64)
        covn[wave][idx] = cov_raw[(size_t)bp * 400 + idx];
    __syncthreads();
    for (int idx = tid; idx < 1080; idx += 256) {
        int m = idx / 360, rem = idx % 360;
        const float* W = (m == 0) ? wq : (m == 1) ? wk : wv;
        Wl[idx] = W[rem] * s2l[rem % 20];
    }
    __syncthreads();

    // trace of s2-scaled cov (broadcast LDS reads, every lane redundantly)
    float tr = 0.f;
#pragma unroll
    for (int f = 0; f < 20; ++f) tr += covn[wave][f * 21] * s2l[f] * s2l[f];
    float trinv = 1.f / tr;

    int grp = lane / 18;
    int jj = lane - grp * 18;
    int m = grp < 3 ? grp : 2;
    int base = grp * 18;
    // Wrow = scaled W_m row jj
    float Wrow[20];
#pragma unroll
    for (int d = 0; d < 20; ++d) Wrow[d] = Wl[m * 360 + jj * 20 + d];
    // u[e] = sum_d covn[e][d] * Wrow[d]  (covn symmetric)
    float u[20];
#pragma unroll
    for (int e = 0; e < 20; ++e) {
        float acc = 0.f;
#pragma unroll
        for (int d = 0; d < 20; ++d) acc += covn[wave][e * 20 + d] * Wrow[d];
        u[e] = acc;
    }
    // a[i] = trinv * sum_e Wl[m][i][e] * u[e]
    float a[18], v[18];
#pragma unroll
    for (int i = 0; i < 18; ++i) {
        float acc = 0.f;
#pragma unroll
        for (int e = 0; e < 20; ++e) acc += Wl[m * 360 + i * 20 + e] * u[e];
        a[i] = acc * trinv;
        v[i] = (i == jj) ? 1.f : 0.f;
    }
    float lam = jacobi18(a, v, jj, base);
    float lw = __logf(fmaxf(lam, 1e-10f));
    if (grp < 3) {
#pragma unroll
        for (int i = 0; i < 18; ++i) Vs[wave][(m * 18 + i) * 18 + jj] = v[i];
        lws[wave][m * 18 + jj] = lw;
    }
    __builtin_amdgcn_wave_barrier();   // wave-synchronous LDS: write->read same wave
    // L = V diag(lw) V^T — triu only (513 = 3*171), mirror to both halves
    for (int idx = lane; idx < 513; idx += 64) {
        int m2 = idx / 171, rem = idx % 171;
        int i = T18.a[rem], jo = T18.b[rem];
        float acc = 0.f;
#pragma unroll
        for (int kk = 0; kk < 18; ++kk)
            acc += Vs[wave][(m2 * 18 + i) * 18 + kk] * lws[wave][m2 * 18 + kk] * Vs[wave][(m2 * 18 + jo) * 18 + kk];
        float* dst = lqkv + (size_t)(bp * 3 + m2) * 324;
        dst[i * 18 + jo] = acc;
        if (i != jo) dst[jo * 18 + i] = acc;
    }
}

// ---------------- K6: log-Euclidean attention -> mixed tangent matrices ----------------
__global__ __launch_bounds__(256) void k6_attn(const float* __restrict__ lqkv,
                                               float* __restrict__ mixed) {
    int b = blockIdx.x, tid = threadIdx.x;
    __shared__ float L[7776];       // [p][m][324]
    __shared__ float sq[8], sk[8], cross[64], prob[64];
    const float* src = lqkv + (size_t)b * 7776;
    for (int idx = tid; idx < 7776; idx += 256) L[idx] = src[idx];
    __syncthreads();
    if (tid < 64) {
        int i = tid >> 3, j = tid & 7;
        const float* fq = &L[(i * 3 + 0) * 324];
        const float* fk = &L[(j * 3 + 1) * 324];
        float cr = 0.f;
        for (int e = 0; e < 324; ++e) cr += fq[e] * fk[e];
        cross[tid] = cr;
    } else if (tid < 72) {
        int i = tid - 64;
        const float* fq = &L[(i * 3 + 0) * 324];
        float s = 0.f;
        for (int e = 0; e < 324; ++e) s += fq[e] * fq[e];
        sq[i] = s;
    } else if (tid < 80) {
        int i = tid - 72;
        const float* fk = &L[(i * 3 + 1) * 324];
        float s = 0.f;
        for (int e = 0; e < 324; ++e) s += fk[e] * fk[e];
        sk[i] = s;
    }
    __syncthreads();
    if (tid < 8) {
        int j = tid;
        float w[8], mx = -1e30f;
        for (int i = 0; i < 8; ++i) {
            float d2 = fmaxf(sq[i] + sk[j] - 2.f * cross[i * 8 + j], 0.0f);
            float en = sqrtf(d2 + 1e-12f);
            w[i] = 1.f / (1.f + log1pf(en));
            mx = fmaxf(mx, w[i]);
        }
        float ssum = 0.f;
        for (int i = 0; i < 8; ++i) { w[i] = __expf(w[i] - mx); ssum += w[i]; }
        float inv = 1.f / ssum;
        for (int i = 0; i < 8; ++i) prob[i * 8 + j] = w[i] * inv;
    }
    __syncthreads();
    float* dst = mixed + (size_t)b * 8 * 324;
    for (int idx = tid; idx < 8 * 324; idx += 256) {
        int j = idx / 324, e = idx % 324;
        float acc = 0.f;
#pragma unroll
        for (int i = 0; i < 8; ++i) acc += prob[i * 8 + j] * L[(i * 3 + 2) * 324 + e];
        dst[idx] = acc;
    }
}

// ---------------- K7: eigh(mixed) -> clamp eigs -> triu vec, Gershgorin fast path ----------------
// 4 waves per block, 3 matrices per wave (12 per block). NO __syncthreads:
// all sync is wave-local (shfl reduce + wave-synchronous LDS slices), so the
// per-wave divergent Gershgorin skip is barrier-safe.
__global__ __launch_bounds__(256) void k7_post(const float* __restrict__ mixed,
                                               float* __restrict__ feat) {
    int tid = threadIdx.x;
    int wave = tid >> 6;
    int lane = tid & 63;
    int blk = blockIdx.x;
    int grp = lane / 18;
    int jj = lane - grp * 18;
    int m = grp < 3 ? grp : 2;
    int base = grp * 18;
    int mat = blk * 12 + wave * 3 + m;
    int matc = mat < 8192 ? mat : 8191;
    __shared__ float Vs[4][972];
    __shared__ float lws[4][54];

    const float* src = mixed + (size_t)matc * 324;
    float a[18], v[18];
#pragma unroll
    for (int i = 0; i < 18; ++i) {
        a[i] = src[i * 18 + jj];
        v[i] = (i == jj) ? 1.f : 0.f;
    }
    // Gershgorin lower bound for this column: diag - sum_{i!=jj}|a[i]| = 2*diag - sum|a[i]|
    float diag = a[0], asum = 0.f;
#pragma unroll
    for (int i = 0; i < 18; ++i) {
        if (jj == i) diag = a[i];
        asum += fabsf(a[i]);
    }
    float gb = 2.f * diag - asum;    // lanes 54..63 hold a duplicate of m=2: harmless
    // wave-min butterfly
#pragma unroll
    for (int off = 32; off; off >>= 1) gb = fminf(gb, __shfl_xor(gb, off, 64));
    const bool skipAll = (gb > -9.2103f);   // wave-uniform; clamp is a no-op -> lt == M

    if (!skipAll) {
        float lam = jacobi18(a, v, jj, base);
        float lw = fmaxf(lam, -9.210340371976182f);   // ln(1e-4)
        if (grp < 3) {
#pragma unroll
            for (int i = 0; i < 18; ++i) Vs[wave][(m * 18 + i) * 18 + jj] = v[i];
            lws[wave][m * 18 + jj] = lw;
        }
    }
    __builtin_amdgcn_wave_barrier();   // wave-synchronous LDS slice
    for (int idx = lane; idx < 513; idx += 64) {
        int m2 = idx / 171, rem = idx % 171;
        int mat2 = blk * 12 + wave * 3 + m2;
        if (mat2 >= 8192) continue;
        int i = T18.a[rem], jo = T18.b[rem];
        float acc;
        if (skipAll) {
            acc = mixed[(size_t)mat2 * 324 + i * 18 + jo];   // lt == M exactly
        } else {
            acc = 0.f;
#pragma unroll
            for (int kk = 0; kk < 18; ++kk)
                acc += Vs[wave][(m2 * 18 + i) * 18 + kk] * lws[wave][m2 * 18 + kk] * Vs[wave][(m2 * 18 + jo) * 18 + kk];
        }
        float scl = (i == jo) ? 1.f : 1.41421356237309515f;
        int bb = mat2 >> 3, pp = mat2 & 7;
        feat[(size_t)bb * 1368 + pp * 171 + rem] = acc * scl;
    }
}

// ---------------- K8: final linear ----------------
__global__ __launch_bounds__(256) void k8_lin(const float* __restrict__ feat,
                                              const float* __restrict__ w_lin,
                                              const float* __restrict__ b_lin,
                                              float* __restrict__ out) {
    int b = blockIdx.x, tid = threadIdx.x;
    int o = tid >> 6, lane = tid & 63;
    const float* fb = feat + (size_t)b * 1368;
    const float* wo = w_lin + o * 1368;
    float acc = 0.f;
    for (int e = lane; e < 1368; e += 64) acc += fb[e] * wo[e];
    for (int off = 32; off; off >>= 1) acc += __shfl_down(acc, off, 64);
    if (lane == 0) out[b * 4 + o] = acc + b_lin[o];
}

// ---------------- launcher ----------------
extern "C" void kernel_launch(void* const* d_in, const int* in_sizes, int n_in,
                              void* d_out, int out_size, void* d_ws, size_t ws_size,
                              hipStream_t stream) {
    (void)in_sizes; (void)n_in; (void)out_size; (void)ws_size;
    const float* x      = (const float*)d_in[0];
    const float* w_spat = (const float*)d_in[1];
    const float* b_spat = (const float*)d_in[2];
    const float* g1     = (const float*)d_in[3];
    const float* be1    = (const float*)d_in[4];
    const float* w_temp = (const float*)d_in[5];
    // d_in[6] = b_temp : cancels in patch covariance -> unused
    const float* g2     = (const float*)d_in[7];
    // d_in[8] = be2 : cancels -> unused
    const float* wq     = (const float*)d_in[9];
    const float* wk     = (const float*)d_in[10];
    const float* wv     = (const float*)d_in[11];
    const float* w_lin  = (const float*)d_in[12];
    const float* b_lin  = (const float*)d_in[13];
    float* ws  = (float*)d_ws;
    float* out = (float*)d_out;

    k0_zero<<<1, 256, 0, stream>>>(ws);
    k1_stats<<<1024, 256, 0, stream>>>(x, ws + OFF_SUMX, ws + OFF_G);
    k2_prep<<<1, 256, 0, stream>>>(w_spat, b_spat, g1, be1, w_temp,
                                   ws + OFF_SUMX, ws + OFF_G,
                                   ws + OFF_MW, ws + OFF_WD, ws + OFF_WDSUM);
    k3_conv<<<8192, 256, 0, stream>>>(x, ws + OFF_MW, ws + OFF_WD, ws + OFF_WDSUM,
                                      ws + OFF_COV, ws + OFF_SUM2, ws + OFF_SUMSQ2);
    k4_s2<<<1, 64, 0, stream>>>(g2, ws + OFF_SUM2, ws + OFF_SUMSQ2, ws + OFF_S2);
    k5_qkv<<<2048, 256, 0, stream>>>(wq, wk, wv, ws + OFF_S2, ws + OFF_COV, ws + OFF_LQKV);
    k6_attn<<<1024, 256, 0, stream>>>(ws + OFF_LQKV, ws + OFF_COV /* mixed reuses cov region */);
    k7_post<<<683, 256, 0, stream>>>(ws + OFF_COV, ws + OFF_FEAT);
    k8_lin<<<1024, 256, 0, stream>>>(ws + OFF_FEAT, w_lin, b_lin, out);
}